// Round 19
// baseline (181.710 us; speedup 1.0000x reference)
//
#include <hip/hip_runtime.h>
#include <hip/hip_bf16.h>

typedef unsigned short u16;
typedef __attribute__((ext_vector_type(4))) float f32x4;
typedef __attribute__((ext_vector_type(8))) short v8s;
typedef __attribute__((ext_vector_type(4))) _Float16 h16x4;
typedef __attribute__((ext_vector_type(2))) unsigned int u32x2;

#define NB 4
#define NT 8
#define NN 128
#define ND 512
#define NH 8
#define NDH 64
#define NS 1024
#define LOG2E 1.4426950408889634f

static __device__ __forceinline__ u16 f2b(float f) {
  __hip_bfloat16 h = __float2bfloat16(f);
  return *reinterpret_cast<u16*>(&h);
}
static __device__ __forceinline__ float b2f(u16 u) {
  __hip_bfloat16 h;
  *reinterpret_cast<u16*>(&h) = u;
  return __bfloat162float(h);
}
// pack 2 f32 -> 2 bf16 in one instruction (no builtin on gfx950; asm per T12)
static __device__ __forceinline__ unsigned int cvtpk(float lo, float hi) {
  unsigned int r;
  asm("v_cvt_pk_bf16_f32 %0, %1, %2" : "=v"(r) : "v"(lo), "v"(hi));
  return r;
}
// single-instruction 2^x (v_exp_f32). Plain exp2f is the PRECISE libm chain.
static __device__ __forceinline__ float fexp2(float x) {
#if __has_builtin(__builtin_amdgcn_exp2f)
  return __builtin_amdgcn_exp2f(x);
#else
  return __expf(x * 0.6931471805599453f);
#endif
}
// async global->LDS, 16B per lane (dest must be wave-linear: base + lane*16)
static __device__ __forceinline__ void gl16(const u16* g, u16* l) {
  __builtin_amdgcn_global_load_lds(
      (const __attribute__((address_space(1))) unsigned int*)g,
      (__attribute__((address_space(3))) unsigned int*)l, 16, 0, 0);
}
// 16x16x16 f16 MFMA
static __device__ __forceinline__ f32x4 mfma16(h16x4 a, h16x4 b, f32x4 c) {
#if __has_builtin(__builtin_amdgcn_mfma_f32_16x16x16f16)
  return __builtin_amdgcn_mfma_f32_16x16x16f16(a, b, c, 0, 0, 0);
#else
  f32x4 d;
  asm volatile("v_mfma_f32_16x16x16_f16 %0, %1, %2, %3\n\ts_nop 7\n\ts_nop 7"
               : "=v"(d)
               : "v"(a), "v"(b), "v"(c));
  return d;
#endif
}
static __device__ __forceinline__ float frcp(float x) { return __builtin_amdgcn_rcpf(x); }

// ---------------- fp32 -> bf16 cast for 4 tensors + coords extraction ------------
__global__ void __launch_bounds__(256) cast4_kernel(const float* __restrict__ s0,
                                                    const float* __restrict__ s1,
                                                    const float* __restrict__ s2,
                                                    const float* __restrict__ s3,
                                                    u16* __restrict__ dst,
                                                    float* __restrict__ crd) {
  int blk = blockIdx.x;
  if (blk >= 4096) {  // coords from x_0 (=s1), (B,S,4) float4 w=0
    for (int i = threadIdx.x; i < 4096; i += 256) {
      float4 v;
      v.x = s1[(size_t)i * ND + 0];
      v.y = s1[(size_t)i * ND + 1];
      v.z = s1[(size_t)i * ND + 2];
      v.w = 0.0f;
      reinterpret_cast<float4*>(crd)[i] = v;
    }
    return;
  }
  int seg = blk >> 10;
  const float* src = seg == 0 ? s0 : (seg == 1 ? s1 : (seg == 2 ? s2 : s3));
  int i = (blk & 1023) * 256 + threadIdx.x;
  const float4* s4 = reinterpret_cast<const float4*>(src) + (size_t)i * 2;
  float4 a = s4[0], b = s4[1];
  u16 r[8] = {f2b(a.x), f2b(a.y), f2b(a.z), f2b(a.w),
              f2b(b.x), f2b(b.y), f2b(b.z), f2b(b.w)};
  *reinterpret_cast<v8s*>(dst + (size_t)seg * 2097152 + (size_t)i * 8) =
      *reinterpret_cast<v8s*>(r);
}

// ---------------- all 5 weight transposes in ONE launch (2048 blocks) ------------
__global__ void __launch_bounds__(256) transpose_all_kernel(const float* __restrict__ Wq,
                                                            const float* __restrict__ Wkv,
                                                            const float* __restrict__ Wo,
                                                            u16* __restrict__ Wqt,
                                                            u16* __restrict__ Wkvt,
                                                            u16* __restrict__ Wot) {
  __shared__ float t[32][33];
  int bid = blockIdx.x;
  const float* W;
  u16* Wt;
  int N, tt;
  if (bid < 256) {
    W = Wq; Wt = Wqt; N = 512; tt = bid;
  } else if (bid < 1792) {
    int f = (bid - 256) >> 9;
    tt = (bid - 256) & 511;
    W = Wkv + (size_t)f * 524288;
    Wt = Wkvt + (size_t)f * 524288;
    N = 1024;
  } else {
    W = Wo; Wt = Wot; N = 512; tt = bid - 1792;
  }
  int ntb = N >> 5;
  int nb = (tt % ntb) * 32, kb = (tt / ntb) * 32;  // K = 512 for all
  int tx = threadIdx.x & 31, ty = threadIdx.x >> 5;
#pragma unroll
  for (int i = 0; i < 4; i++) {
    int r = ty + i * 8;
    t[r][tx] = W[(size_t)(kb + r) * N + nb + tx];
  }
  __syncthreads();
#pragma unroll
  for (int i = 0; i < 4; i++) {
    int r = ty + i * 8;
    Wt[(size_t)(nb + r) * 512 + kb + tx] = f2b(t[tx][r]);
  }
}

// ---------------- q + kv projection GEMMs, ONE 896-block launch ------------------
// blocks [0,128): q-proj (mode 0); [128,896): kv-proj (f=(bid-128)>>8).
// m97 structure: 128x128 tile, BK=32, gl16 fragment staging, double-buffered.
__global__ void __launch_bounds__(256) gemm_qkv_kernel(
    const u16* __restrict__ Aq, const u16* __restrict__ Wqt,
    const float* __restrict__ bq, const float* __restrict__ dnm,
    u16* __restrict__ qr, const u16* __restrict__ Af,
    const u16* __restrict__ Wkvt, const float* __restrict__ bkv,
    u16* __restrict__ kr, u16* __restrict__ vtr) {
  __shared__ __align__(16) u16 sbuf[2 * 8192];
  int bid0 = blockIdx.x;
  int tid = threadIdx.x;
  int lane = tid & 63, wave = tid >> 6;
  int g = lane >> 4, li = lane & 15;
  int mode, f, bid, N;
  const u16 *A, *Wt;
  const float* bv;
  if (bid0 < 128) {
    mode = 0; f = 0; bid = bid0; N = 512; A = Aq; Wt = Wqt; bv = bq;
  } else {
    mode = 1;
    int t = bid0 - 128;
    f = t >> 8; bid = t & 255; N = 1024;
    A = Af + (size_t)f * 2097152;
    Wt = Wkvt + (size_t)f * 524288;
    bv = bkv + f * 1024;
  }
  const int K = 512;
  int nt = N >> 7;
  int by = bid / nt, bx = bid % nt;
  int wr = (wave & 1) * 64, wc = (wave >> 1) * 64;
  f32x4 acc[4][4] = {};
  const u16* srcs[4];
  int dsts[4];
#pragma unroll
  for (int j = 0; j < 4; j++) {
    int c = wave * 4 + j;
    if (c < 8)
      srcs[j] = A + (size_t)(by * 128 + c * 16 + li) * K + g * 8;
    else
      srcs[j] = Wt + (size_t)(bx * 128 + (c - 8) * 16 + li) * K + g * 8;
    dsts[j] = c * 512 + lane * 8;
  }
#pragma unroll
  for (int j = 0; j < 4; j++) gl16(srcs[j], sbuf + dsts[j]);
  for (int t = 0; t < 16; t++) {
    int p = t & 1;
    if (t < 15) {
#pragma unroll
      for (int j = 0; j < 4; j++)
        gl16(srcs[j] + (t + 1) * 32, sbuf + (p ^ 1) * 8192 + dsts[j]);
      asm volatile("s_waitcnt vmcnt(4)" ::: "memory");
    } else {
      asm volatile("s_waitcnt vmcnt(0)" ::: "memory");
    }
    __builtin_amdgcn_s_barrier();
    __builtin_amdgcn_sched_barrier(0);
    const u16* bufb = sbuf + p * 8192;
    v8s a[4], b[4];
#pragma unroll
    for (int mi = 0; mi < 4; mi++)
      a[mi] = *reinterpret_cast<const v8s*>(bufb + ((wr >> 4) + mi) * 512 + lane * 8);
#pragma unroll
    for (int ni = 0; ni < 4; ni++)
      b[ni] = *reinterpret_cast<const v8s*>(bufb + 4096 + ((wc >> 4) + ni) * 512 + lane * 8);
    __builtin_amdgcn_s_setprio(1);
#pragma unroll
    for (int mi = 0; mi < 4; mi++)
#pragma unroll
      for (int ni = 0; ni < 4; ni++)
        acc[mi][ni] =
            __builtin_amdgcn_mfma_f32_16x16x32_bf16(a[mi], b[ni], acc[mi][ni], 0, 0, 0);
    __builtin_amdgcn_s_setprio(0);
    __builtin_amdgcn_s_barrier();
  }
#pragma unroll
  for (int mi = 0; mi < 4; mi++)
#pragma unroll
    for (int ni = 0; ni < 4; ni++) {
      int n = bx * 128 + wc + ni * 16 + li;
      float bn = bv[n];
      int mbase = by * 128 + wr + mi * 16 + 4 * g;
      bool isv = (mode == 1) && (n >= 512);
      if (!isv) {
        int d = n & 63, h = (n & 511) >> 6;
        int j = d >> 1;
        float freq = __expf(-(float)j * 0.21586735246819178f);
        float sca = (mode == 0) ? frcp(dnm[h]) * LOG2E : 1.0f;
#pragma unroll
        for (int r = 0; r < 4; r++) {
          int mrow = mbase + r;
          int b = mrow >> 10, s = mrow & 1023;
          float val = acc[mi][ni][r] + bn;
          float partner = __shfl_xor(val, 1);
          float ang = (float)(s >> 7) * freq;
          float sn = __sinf(ang), cs = __cosf(ang);
          float res = (n & 1) ? (partner * sn + val * cs) : (val * cs - partner * sn);
          res *= sca;
          size_t idx;
          if (mode == 0)
            idx = ((size_t)(b * NH + h) * NS + s) * NDH + d;
          else
            idx = ((size_t)((f * NB + b) * NH + h) * NS + s) * NDH + d;
          (mode == 0 ? qr : kr)[idx] = f2b(res);
        }
      } else {
        int vd = n - 512;
        int h = vd >> 6, d = vd & 63;
        int b = mbase >> 10, s0 = mbase & 1023;
        u16 pk[4];
#pragma unroll
        for (int r = 0; r < 4; r++) pk[r] = f2b(acc[mi][ni][r] + bn);
        u16* dst = vtr + ((size_t)((f * NB + b) * NH + h) * NDH + d) * NS + s0;
        *reinterpret_cast<ushort4*>(dst) = *reinterpret_cast<ushort4*>(pk);
      }
    }
}

// ---------------- SH-bias MLP, STANDALONE (zero LDS -> 8 blocks/CU occupancy) ----
// Latency-chain-bound kernel: TLP is the hiding mechanism; fused-kernel LDS
// reservation capped it at 5 blocks/CU (R17/R18 lesson).
__global__ void __launch_bounds__(256) bias_kernel(const float* __restrict__ coords,
                                                   const float* __restrict__ W1,
                                                   const float* __restrict__ b1,
                                                   const float* __restrict__ W2,
                                                   const float* __restrict__ b2,
                                                   const float* __restrict__ W3,
                                                   const float* __restrict__ b3,
                                                   u16* __restrict__ biasF) {
  int wave = threadIdx.x >> 6, lane = threadIdx.x & 63;
  int g = lane >> 4, li = lane & 15;
  int id = blockIdx.x * 4 + wave;  // 8192 = b(4) x qt(64) x kt(32)
  int kt = id & 31, qt = (id >> 5) & 63, b = id >> 11;
  const float Y0 = 0.28209479177387814f;
  const float Y1 = 0.4886025119029199f;

  h16x4 A1 = {}, A2, A3;
#pragma unroll
  for (int r = 0; r < 4; r++) {
    A1[r] = (g == 0) ? (_Float16)W1[r * 16 + li] : (_Float16)0.0f;
    A2[r] = (_Float16)W2[(4 * g + r) * 16 + li];
    A3[r] = (li < 8) ? (_Float16)(W3[(4 * g + r) * 8 + li] * LOG2E) : (_Float16)0.0f;
  }
  f32x4 b1g = reinterpret_cast<const f32x4*>(b1)[g];
  f32x4 b2g = reinterpret_cast<const f32x4*>(b2)[g];
  f32x4 b3g = {0.f, 0.f, 0.f, 0.f};
  if (g < 2) b3g = reinterpret_cast<const f32x4*>(b3)[g] * LOG2E;

  const float4* crd4 = reinterpret_cast<const float4*>(coords);
  float4 cq = crd4[b * NS + qt * 16 + li];
  f32x4 zero = {0.f, 0.f, 0.f, 0.f};

  for (int gkc = 0; gkc < 4; gkc++) {
    unsigned int resw[4][4];
    float prev[4];
#pragma unroll
    for (int j = 0; j < 8; j++) {
      int k = kt * 32 + (j >> 2) * 16 + gkc * 4 + (j & 3);
      float4 ck = crd4[b * NS + k];
      float rx = cq.x - ck.x;
      float ry = cq.y - ck.y;
      float rz = cq.z - ck.z;
      float d2 = rx * rx + ry * ry + rz * rz;
      float inv = __builtin_amdgcn_rsqf(fmaxf(d2, 1e-20f));
      h16x4 B1 = {};
      if (g == 0) {
        B1[0] = (_Float16)Y0;
        B1[1] = (_Float16)(Y1 * ry * inv);
        B1[2] = (_Float16)(Y1 * rz * inv);
        B1[3] = (_Float16)(Y1 * rx * inv);
      }
      f32x4 c1 = mfma16(A1, B1, zero);
      h16x4 B2;
#pragma unroll
      for (int r = 0; r < 4; r++) {
        float a = c1[r] + b1g[r];
        B2[r] = (_Float16)(a * frcp(1.0f + __expf(-a)));
      }
      f32x4 c2 = mfma16(A2, B2, zero);
      h16x4 B3;
#pragma unroll
      for (int r = 0; r < 4; r++) {
        float a = c2[r] + b2g[r];
        B3[r] = (_Float16)(a * frcp(1.0f + __expf(-a)));
      }
      f32x4 c3 = mfma16(A3, B3, zero);
#pragma unroll
      for (int r = 0; r < 4; r++) {
        float val = c3[r] + b3g[r];
        if (j & 1)
          resw[r][j >> 1] = cvtpk(prev[r], val);
        else
          prev[r] = val;
      }
    }
    if (g < 2) {
      size_t coff = ((size_t)(qt * 32 + kt) * 64 + gkc * 16 + li) * 8;
#pragma unroll
      for (int r = 0; r < 4; r++) {
        u16* dst = biasF + (size_t)(b * NH + 4 * g + r) * 1048576 + coff;
        *reinterpret_cast<uint4*>(dst) = *reinterpret_cast<uint4*>(resw[r]);
      }
    }
  }
}

// ---------------- out-projection GEMM (m97 structure) ----------------------------
__global__ void __launch_bounds__(256) gemm_out_kernel(const u16* __restrict__ A,
                                                       const u16* __restrict__ Wt,
                                                       const float* __restrict__ bias,
                                                       float* __restrict__ outF) {
  __shared__ __align__(16) u16 sbuf[2 * 8192];
  const int N = 512, K = 512;
  int bid = blockIdx.x;
  int nt = N >> 7;
  int by = bid / nt, bx = bid % nt;
  int tid = threadIdx.x;
  int lane = tid & 63, wave = tid >> 6;
  int g = lane >> 4, li = lane & 15;
  int wr = (wave & 1) * 64, wc = (wave >> 1) * 64;
  f32x4 acc[4][4] = {};
  const u16* srcs[4];
  int dsts[4];
#pragma unroll
  for (int j = 0; j < 4; j++) {
    int c = wave * 4 + j;
    if (c < 8)
      srcs[j] = A + (size_t)(by * 128 + c * 16 + li) * K + g * 8;
    else
      srcs[j] = Wt + (size_t)(bx * 128 + (c - 8) * 16 + li) * K + g * 8;
    dsts[j] = c * 512 + lane * 8;
  }
#pragma unroll
  for (int j = 0; j < 4; j++) gl16(srcs[j], sbuf + dsts[j]);
  for (int t = 0; t < 16; t++) {
    int p = t & 1;
    if (t < 15) {
#pragma unroll
      for (int j = 0; j < 4; j++)
        gl16(srcs[j] + (t + 1) * 32, sbuf + (p ^ 1) * 8192 + dsts[j]);
      asm volatile("s_waitcnt vmcnt(4)" ::: "memory");
    } else {
      asm volatile("s_waitcnt vmcnt(0)" ::: "memory");
    }
    __builtin_amdgcn_s_barrier();
    __builtin_amdgcn_sched_barrier(0);
    const u16* bufb = sbuf + p * 8192;
    v8s a[4], b[4];
#pragma unroll
    for (int mi = 0; mi < 4; mi++)
      a[mi] = *reinterpret_cast<const v8s*>(bufb + ((wr >> 4) + mi) * 512 + lane * 8);
#pragma unroll
    for (int ni = 0; ni < 4; ni++)
      b[ni] = *reinterpret_cast<const v8s*>(bufb + 4096 + ((wc >> 4) + ni) * 512 + lane * 8);
    __builtin_amdgcn_s_setprio(1);
#pragma unroll
    for (int mi = 0; mi < 4; mi++)
#pragma unroll
      for (int ni = 0; ni < 4; ni++)
        acc[mi][ni] = __builtin_amdgcn_mfma_f32_16x16x32_bf16(a[mi], b[ni], acc[mi][ni], 0, 0, 0);
    __builtin_amdgcn_s_setprio(0);
    __builtin_amdgcn_s_barrier();
  }
#pragma unroll
  for (int mi = 0; mi < 4; mi++)
#pragma unroll
    for (int ni = 0; ni < 4; ni++) {
      int n = bx * 128 + wc + ni * 16 + li;
      float bn = bias[n];
      int mbase = by * 128 + wr + mi * 16 + 4 * g;
#pragma unroll
      for (int r = 0; r < 4; r++)
        outF[(size_t)(mbase + r) * N + n] = acc[mi][ni][r] + bn;
    }
}

// ---------------- fused flash attention (R15-proven: double-buffer, fexp2) -------
#define ATTN_LDSB 12288  // u16 per buffer (24KB)
__global__ void __launch_bounds__(768, 6) attn_kernel(const u16* __restrict__ q,
                                                      const u16* __restrict__ kmat,
                                                      const u16* __restrict__ vt,
                                                      const u16* __restrict__ biasF,
                                                      const float* __restrict__ fw,
                                                      u16* __restrict__ attno) {
  __shared__ __align__(16) u16 sbuf[2 * ATTN_LDSB];
  int d = blockIdx.x;
  int x = d & 7, u = d >> 3;
  int bh = x * 4 + (u & 3);  // 16 blocks per bh share one XCD
  int qb = u >> 2;
  int h = bh & 7, b = bh >> 3;
  int wave = threadIdx.x >> 6, lane = threadIdx.x & 63;
  int g = lane >> 4, li = lane & 15;
  int ff = wave >> 2, qtl = wave & 3;
  int qt = qb * 4 + qtl;

  float f0 = fw[0], f1 = fw[1], f2v = fw[2];
  float mxg = fmaxf(fmaxf(f0, f1), f2v);
  float e0 = __expf(f0 - mxg), e1 = __expf(f1 - mxg), e2 = __expf(f2v - mxg);
  float es = e0 + e1 + e2;
  float gate = (ff == 0 ? e0 : (ff == 1 ? e1 : e2)) / es;

  const u16* qbase = q + ((size_t)bh * NS + qt * 16 + li) * NDH + g * 8;
  v8s qa0 = *reinterpret_cast<const v8s*>(qbase);
  v8s qa1 = *reinterpret_cast<const v8s*>(qbase + 32);
  const u16* bfrag = biasF + (size_t)bh * 1048576 + (size_t)qt * 16384;

  auto stage = [&](int kt, int p) {
    int k0 = kt * 32;
    u16* bufb = sbuf + p * ATTN_LDSB;
#pragma unroll
    for (int j = 0; j < 2; j++) {
      int c = wave * 2 + j;
      if (c < 12) {
        int cf = c >> 2, kks = (c >> 1) & 1, hf = c & 1;
        const u16* src = kmat + ((size_t)(cf * 32 + bh) * NS + k0 + kks * 16 + li) * NDH +
                         hf * 32 + g * 8;
        gl16(src, bufb + cf * 2048 + (c & 3) * 512 + lane * 8);
      } else {
        int cc = c - 12, cf = cc >> 2, ni = cc & 3;
        const u16* src = vt + ((size_t)(cf * 32 + bh) * NDH + ni * 16 + li) * NS + k0 + g * 8;
        gl16(src, bufb + 6144 + cf * 2048 + ni * 512 + lane * 8);
      }
    }
  };

  float m = 0.f;   // wave-uniform deferred max (log2 units)
  float lr = 0.f;
  f32x4 o[4] = {};
  f32x4 zero = {0.f, 0.f, 0.f, 0.f};
  int s0lane = ((g & 1) << 5) + li;  // fallback path only
  int kksT = g >> 1;

  stage(0, 0);

  for (int t = 0; t < 32; t++) {
    int p = t & 1;
    v8s bb = *reinterpret_cast<const v8s*>(bfrag + ((size_t)t * 64 + lane) * 8);
    if (t < 31) {
      stage(t + 1, p ^ 1);
      asm volatile("s_waitcnt vmcnt(2)" ::: "memory");
    } else {
      asm volatile("s_waitcnt vmcnt(0)" ::: "memory");
    }
    __builtin_amdgcn_s_barrier();
    __builtin_amdgcn_sched_barrier(0);
    const u16* bufb = sbuf + p * ATTN_LDSB;
    v8s kf[2][2];
#pragma unroll
    for (int kks = 0; kks < 2; kks++)
#pragma unroll
      for (int hf = 0; hf < 2; hf++)
        kf[kks][hf] = *reinterpret_cast<const v8s*>(
            bufb + ff * 2048 + (kks * 2 + hf) * 512 + lane * 8);
    float pv[2][4];
    __builtin_amdgcn_s_setprio(1);
#pragma unroll
    for (int kks = 0; kks < 2; kks++) {
      f32x4 sc = __builtin_amdgcn_mfma_f32_16x16x32_bf16(kf[kks][0], qa0, zero, 0, 0, 0);
      sc = __builtin_amdgcn_mfma_f32_16x16x32_bf16(kf[kks][1], qa1, sc, 0, 0, 0);
#pragma unroll
      for (int r = 0; r < 4; r++)
        pv[kks][r] = sc[r] + b2f((u16)bb[kks * 4 + r]);  // q,bias pre-scaled by log2e
    }
    __builtin_amdgcn_s_setprio(0);
    float pmax = fmaxf(fmaxf(fmaxf(pv[0][0], pv[0][1]), pv[0][2]),
                       fmaxf(fmaxf(pv[0][3], pv[1][0]), pv[1][1]));
    pmax = fmaxf(fmaxf(pmax, pv[1][2]), pv[1][3]);
    if (!__all(pmax - m <= 11.0f)) {  // rare: raise wave-uniform max (2^11 headroom)
      float rm = pmax;
      rm = fmaxf(rm, __shfl_xor(rm, 1));
      rm = fmaxf(rm, __shfl_xor(rm, 2));
      rm = fmaxf(rm, __shfl_xor(rm, 4));
      rm = fmaxf(rm, __shfl_xor(rm, 8));
      rm = fmaxf(rm, __shfl_xor(rm, 16));
      rm = fmaxf(rm, __shfl_xor(rm, 32));
      float sc2 = fexp2(m - rm);
      lr *= sc2;
#pragma unroll
      for (int ni = 0; ni < 4; ni++)
#pragma unroll
        for (int r = 0; r < 4; r++) o[ni][r] *= sc2;
      m = rm;
    }
    float p2[2][4];
#pragma unroll
    for (int kks = 0; kks < 2; kks++)
#pragma unroll
      for (int r = 0; r < 4; r++) {
        p2[kks][r] = fexp2(pv[kks][r] - m);  // single v_exp_f32
        lr += p2[kks][r];
      }
    unsigned int pA0 = cvtpk(p2[0][0], p2[0][1]);
    unsigned int pA1 = cvtpk(p2[0][2], p2[0][3]);
    unsigned int pB0 = cvtpk(p2[1][0], p2[1][1]);
    unsigned int pB1 = cvtpk(p2[1][2], p2[1][3]);
    int warr[4];
#if __has_builtin(__builtin_amdgcn_permlane32_swap) && \
    __has_builtin(__builtin_amdgcn_permlane16_swap)
    {
      u32x2 r0 = __builtin_amdgcn_permlane32_swap(pA0, pB0, false, false);
      u32x2 r1 = __builtin_amdgcn_permlane32_swap(pA1, pB1, false, false);
      u32x2 s0 = __builtin_amdgcn_permlane16_swap(r0[0], r0[1], false, false);
      u32x2 s1 = __builtin_amdgcn_permlane16_swap(r1[0], r1[1], false, false);
      warr[0] = s0[0];
      warr[1] = s1[0];
      warr[2] = s0[1];
      warr[3] = s1[1];
    }
#else
    {
      int a00 = __shfl((int)pA0, s0lane), a01 = __shfl((int)pA1, s0lane);
      int a10 = __shfl((int)pB0, s0lane), a11 = __shfl((int)pB1, s0lane);
      int c00 = __shfl((int)pA0, s0lane + 16), c01 = __shfl((int)pA1, s0lane + 16);
      int c10 = __shfl((int)pB0, s0lane + 16), c11 = __shfl((int)pB1, s0lane + 16);
      warr[0] = kksT ? a10 : a00;
      warr[1] = kksT ? a11 : a01;
      warr[2] = kksT ? c10 : c00;
      warr[3] = kksT ? c11 : c01;
    }
#endif
    v8s pa = *reinterpret_cast<v8s*>(warr);
    __builtin_amdgcn_s_setprio(1);
#pragma unroll
    for (int ni = 0; ni < 4; ni++) {
      v8s vb = *reinterpret_cast<const v8s*>(bufb + 6144 + ff * 2048 + ni * 512 + lane * 8);
      o[ni] = __builtin_amdgcn_mfma_f32_16x16x32_bf16(pa, vb, o[ni], 0, 0, 0);
    }
    __builtin_amdgcn_s_setprio(0);
    __builtin_amdgcn_s_barrier();
  }
  float l = lr;
  l += __shfl_xor(l, 16);
  l += __shfl_xor(l, 32);
  float scl = gate / l;
  float srow[4];
#pragma unroll
  for (int r = 0; r < 4; r++)
    srow[r] = __shfl(scl, (lane & 48) | (((lane >> 2) & 12) + r));
  float out[4][4];
#pragma unroll
  for (int ni = 0; ni < 4; ni++)
#pragma unroll
    for (int r = 0; r < 4; r++) out[ni][r] = o[ni][r] * srow[r];

  float* part = reinterpret_cast<float*>(sbuf);  // [8][16][68] padded
  if (ff > 0) {
    int fq = (ff - 1) * 4 + qtl;
#pragma unroll
    for (int ni = 0; ni < 4; ni++)
#pragma unroll
      for (int r = 0; r < 4; r++)
        part[fq * 1088 + (4 * g + r) * 68 + ni * 16 + li] = out[ni][r];
  }
  __syncthreads();
  if (ff == 0) {
#pragma unroll
    for (int ni = 0; ni < 4; ni++)
#pragma unroll
      for (int r = 0; r < 4; r++) {
        float v = out[ni][r] + part[qtl * 1088 + (4 * g + r) * 68 + ni * 16 + li] +
                  part[(4 + qtl) * 1088 + (4 * g + r) * 68 + ni * 16 + li];
        attno[((size_t)(b * NS + qt * 16 + 4 * g + r)) * ND + h * NDH + ni * 16 + li] =
            f2b(v);
      }
  }
}

extern "C" void kernel_launch(void* const* d_in, const int* in_sizes, int n_in,
                              void* d_out, int out_size, void* d_ws, size_t ws_size,
                              hipStream_t stream) {
  const float* x0 = (const float*)d_in[0];
  const float* v0 = (const float*)d_in[1];
  const float* cf = (const float*)d_in[2];
  const float* qd = (const float*)d_in[3];
  const float* Wq = (const float*)d_in[4];
  const float* bq = (const float*)d_in[5];
  const float* Wkv = (const float*)d_in[6];
  const float* bkv = (const float*)d_in[7];
  const float* Wo = (const float*)d_in[8];
  const float* bo = (const float*)d_in[9];
  const float* fw = (const float*)d_in[10];
  const float* dnm = (const float*)d_in[11];
  const float* W1 = (const float*)d_in[12];
  const float* b1 = (const float*)d_in[13];
  const float* W2 = (const float*)d_in[14];
  const float* b2 = (const float*)d_in[15];
  const float* W3 = (const float*)d_in[16];
  const float* b3 = (const float*)d_in[17];

  char* ws = (char*)d_ws;
  size_t off = 0;
  auto alloc = [&](size_t bytes) -> void* {
    void* p = ws + off;
    off = (off + bytes + 255) & ~(size_t)255;
    return p;
  };
  const size_t E = 4096ull * 512;
  u16* Aq = (u16*)alloc(E * 2);
  u16* Af = (u16*)alloc(3 * E * 2);  // contiguous after Aq (cast4 relies on this)
  u16* Wqt = (u16*)alloc(262144ull * 2);
  u16* Wkvt = (u16*)alloc(3ull * 524288 * 2);
  u16* Wot = (u16*)alloc(262144ull * 2);
  float* crd = (float*)alloc(4096ull * 4 * 4);
  u16* qr = (u16*)alloc(E * 2);
  u16* kr = (u16*)alloc(3 * E * 2);
  u16* vtr = (u16*)alloc(3 * E * 2);
  u16* biasF = (u16*)alloc(33554432ull * 2);
  u16* attno = (u16*)alloc(E * 2);
  (void)ws_size; (void)in_sizes; (void)n_in; (void)out_size; (void)Af;

  cast4_kernel<<<4097, 256, 0, stream>>>(qd, x0, v0, cf, Aq, crd);
  transpose_all_kernel<<<2048, 256, 0, stream>>>(Wq, Wkv, Wo, Wqt, Wkvt, Wot);
  gemm_qkv_kernel<<<896, 256, 0, stream>>>(Aq, Wqt, bq, dnm, qr, Af, Wkvt, bkv, kr, vtr);
  bias_kernel<<<2048, 256, 0, stream>>>(crd, W1, b1, W2, b2, W3, b3, biasF);
  attn_kernel<<<512, 768, 0, stream>>>(qr, kr, vtr, biasF, fw, attno);
  gemm_out_kernel<<<128, 256, 0, stream>>>(attno, Wot, bo, (float*)d_out);
}

// Round 20
// 174.803 us; speedup vs baseline: 1.0395x; 1.0395x over previous
//
#include <hip/hip_runtime.h>
#include <hip/hip_bf16.h>

typedef unsigned short u16;
typedef __attribute__((ext_vector_type(4))) float f32x4;
typedef __attribute__((ext_vector_type(8))) short v8s;
typedef __attribute__((ext_vector_type(4))) _Float16 h16x4;
typedef __attribute__((ext_vector_type(2))) unsigned int u32x2;

#define NB 4
#define NT 8
#define NN 128
#define ND 512
#define NH 8
#define NDH 64
#define NS 1024
#define LOG2E 1.4426950408889634f

static __device__ __forceinline__ u16 f2b(float f) {
  __hip_bfloat16 h = __float2bfloat16(f);
  return *reinterpret_cast<u16*>(&h);
}
static __device__ __forceinline__ float b2f(u16 u) {
  __hip_bfloat16 h;
  *reinterpret_cast<u16*>(&h) = u;
  return __bfloat162float(h);
}
// pack 2 f32 -> 2 bf16 in one instruction (no builtin on gfx950; asm per T12)
static __device__ __forceinline__ unsigned int cvtpk(float lo, float hi) {
  unsigned int r;
  asm("v_cvt_pk_bf16_f32 %0, %1, %2" : "=v"(r) : "v"(lo), "v"(hi));
  return r;
}
// single-instruction 2^x (v_exp_f32). Plain exp2f is the PRECISE libm chain.
static __device__ __forceinline__ float fexp2(float x) {
#if __has_builtin(__builtin_amdgcn_exp2f)
  return __builtin_amdgcn_exp2f(x);
#else
  return __expf(x * 0.6931471805599453f);
#endif
}
// async global->LDS, 16B per lane (dest must be wave-linear: base + lane*16)
static __device__ __forceinline__ void gl16(const u16* g, u16* l) {
  __builtin_amdgcn_global_load_lds(
      (const __attribute__((address_space(1))) unsigned int*)g,
      (__attribute__((address_space(3))) unsigned int*)l, 16, 0, 0);
}
// 16x16x16 f16 MFMA
static __device__ __forceinline__ f32x4 mfma16(h16x4 a, h16x4 b, f32x4 c) {
#if __has_builtin(__builtin_amdgcn_mfma_f32_16x16x16f16)
  return __builtin_amdgcn_mfma_f32_16x16x16f16(a, b, c, 0, 0, 0);
#else
  f32x4 d;
  asm volatile("v_mfma_f32_16x16x16_f16 %0, %1, %2, %3\n\ts_nop 7\n\ts_nop 7"
               : "=v"(d)
               : "v"(a), "v"(b), "v"(c));
  return d;
#endif
}
static __device__ __forceinline__ float frcp(float x) { return __builtin_amdgcn_rcpf(x); }

// ---------------- PRE: casts + coords + all 5 weight transposes, ONE launch ------
// blocks [0,4096): fp32->bf16 cast of 4 activation tensors; 4096: coords;
// [4097,6145): 32x32 transpose tiles of Wq/Wkv/Wo.
__global__ void __launch_bounds__(256) pre_kernel(const float* __restrict__ s0,
                                                  const float* __restrict__ s1,
                                                  const float* __restrict__ s2,
                                                  const float* __restrict__ s3,
                                                  u16* __restrict__ dst,
                                                  float* __restrict__ crd,
                                                  const float* __restrict__ Wq,
                                                  const float* __restrict__ Wkv,
                                                  const float* __restrict__ Wo,
                                                  u16* __restrict__ Wqt,
                                                  u16* __restrict__ Wkvt,
                                                  u16* __restrict__ Wot) {
  __shared__ float t[32][33];
  int blk = blockIdx.x;
  if (blk < 4096) {  // cast path
    int seg = blk >> 10;
    const float* src = seg == 0 ? s0 : (seg == 1 ? s1 : (seg == 2 ? s2 : s3));
    int i = (blk & 1023) * 256 + threadIdx.x;
    const float4* s4 = reinterpret_cast<const float4*>(src) + (size_t)i * 2;
    float4 a = s4[0], b = s4[1];
    u16 r[8] = {f2b(a.x), f2b(a.y), f2b(a.z), f2b(a.w),
                f2b(b.x), f2b(b.y), f2b(b.z), f2b(b.w)};
    *reinterpret_cast<v8s*>(dst + (size_t)seg * 2097152 + (size_t)i * 8) =
        *reinterpret_cast<v8s*>(r);
    return;
  }
  if (blk == 4096) {  // coords from x_0 (=s1), (B,S,4) float4 w=0
    for (int i = threadIdx.x; i < 4096; i += 256) {
      float4 v;
      v.x = s1[(size_t)i * ND + 0];
      v.y = s1[(size_t)i * ND + 1];
      v.z = s1[(size_t)i * ND + 2];
      v.w = 0.0f;
      reinterpret_cast<float4*>(crd)[i] = v;
    }
    return;
  }
  // transpose path
  int bid = blk - 4097;
  const float* W;
  u16* Wt;
  int N, tt;
  if (bid < 256) {
    W = Wq; Wt = Wqt; N = 512; tt = bid;
  } else if (bid < 1792) {
    int f = (bid - 256) >> 9;
    tt = (bid - 256) & 511;
    W = Wkv + (size_t)f * 524288;
    Wt = Wkvt + (size_t)f * 524288;
    N = 1024;
  } else {
    W = Wo; Wt = Wot; N = 512; tt = bid - 1792;
  }
  int ntb = N >> 5;
  int nb = (tt % ntb) * 32, kb = (tt / ntb) * 32;  // K = 512 for all
  int tx = threadIdx.x & 31, ty = threadIdx.x >> 5;
#pragma unroll
  for (int i = 0; i < 4; i++) {
    int r = ty + i * 8;
    t[r][tx] = W[(size_t)(kb + r) * N + nb + tx];
  }
  __syncthreads();
#pragma unroll
  for (int i = 0; i < 4; i++) {
    int r = ty + i * 8;
    Wt[(size_t)(nb + r) * 512 + kb + tx] = f2b(t[tx][r]);
  }
}

// ---------------- FUSED mid section: q-proj + kv-proj GEMMs + SH-bias MLP --------
// blocks [0,128): q-proj (mode 0); [128,896): kv-proj (mode 1, f=(bid-128)>>8);
// [896,2944): bias MLP. (R17 layout — best measured; interleave/split were null.)
__global__ void __launch_bounds__(256) mid_kernel(
    const u16* __restrict__ Aq, const u16* __restrict__ Wqt,
    const float* __restrict__ bq, const float* __restrict__ dnm,
    u16* __restrict__ qr, const u16* __restrict__ Af,
    const u16* __restrict__ Wkvt, const float* __restrict__ bkv,
    u16* __restrict__ kr, u16* __restrict__ vtr,
    const float* __restrict__ coords, const float* __restrict__ W1,
    const float* __restrict__ b1, const float* __restrict__ W2,
    const float* __restrict__ b2, const float* __restrict__ W3,
    const float* __restrict__ b3, u16* __restrict__ biasF) {
  __shared__ __align__(16) u16 sbuf[2 * 8192];
  int bid0 = blockIdx.x;
  int tid = threadIdx.x;
  int lane = tid & 63, wave = tid >> 6;
  int g = lane >> 4, li = lane & 15;

  if (bid0 < 896) {  // ---------------- GEMM path (m97 structure, 128x128, BK=32)
    int mode, f, bid, N;
    const u16 *A, *Wt;
    const float* bv;
    if (bid0 < 128) {
      mode = 0; f = 0; bid = bid0; N = 512; A = Aq; Wt = Wqt; bv = bq;
    } else {
      mode = 1;
      int t = bid0 - 128;
      f = t >> 8; bid = t & 255; N = 1024;
      A = Af + (size_t)f * 2097152;
      Wt = Wkvt + (size_t)f * 524288;
      bv = bkv + f * 1024;
    }
    const int K = 512;
    int nt = N >> 7;
    int by = bid / nt, bx = bid % nt;
    int wr = (wave & 1) * 64, wc = (wave >> 1) * 64;
    f32x4 acc[4][4] = {};
    const u16* srcs[4];
    int dsts[4];
#pragma unroll
    for (int j = 0; j < 4; j++) {
      int c = wave * 4 + j;
      if (c < 8)
        srcs[j] = A + (size_t)(by * 128 + c * 16 + li) * K + g * 8;
      else
        srcs[j] = Wt + (size_t)(bx * 128 + (c - 8) * 16 + li) * K + g * 8;
      dsts[j] = c * 512 + lane * 8;
    }
#pragma unroll
    for (int j = 0; j < 4; j++) gl16(srcs[j], sbuf + dsts[j]);
    for (int t = 0; t < 16; t++) {
      int p = t & 1;
      if (t < 15) {
#pragma unroll
        for (int j = 0; j < 4; j++)
          gl16(srcs[j] + (t + 1) * 32, sbuf + (p ^ 1) * 8192 + dsts[j]);
        asm volatile("s_waitcnt vmcnt(4)" ::: "memory");
      } else {
        asm volatile("s_waitcnt vmcnt(0)" ::: "memory");
      }
      __builtin_amdgcn_s_barrier();
      __builtin_amdgcn_sched_barrier(0);
      const u16* bufb = sbuf + p * 8192;
      v8s a[4], b[4];
#pragma unroll
      for (int mi = 0; mi < 4; mi++)
        a[mi] = *reinterpret_cast<const v8s*>(bufb + ((wr >> 4) + mi) * 512 + lane * 8);
#pragma unroll
      for (int ni = 0; ni < 4; ni++)
        b[ni] = *reinterpret_cast<const v8s*>(bufb + 4096 + ((wc >> 4) + ni) * 512 + lane * 8);
      __builtin_amdgcn_s_setprio(1);
#pragma unroll
      for (int mi = 0; mi < 4; mi++)
#pragma unroll
        for (int ni = 0; ni < 4; ni++)
          acc[mi][ni] =
              __builtin_amdgcn_mfma_f32_16x16x32_bf16(a[mi], b[ni], acc[mi][ni], 0, 0, 0);
      __builtin_amdgcn_s_setprio(0);
      __builtin_amdgcn_s_barrier();
    }
#pragma unroll
    for (int mi = 0; mi < 4; mi++)
#pragma unroll
      for (int ni = 0; ni < 4; ni++) {
        int n = bx * 128 + wc + ni * 16 + li;
        float bn = bv[n];
        int mbase = by * 128 + wr + mi * 16 + 4 * g;
        bool isv = (mode == 1) && (n >= 512);
        if (!isv) {
          int d = n & 63, h = (n & 511) >> 6;
          int j = d >> 1;
          float freq = __expf(-(float)j * 0.21586735246819178f);
          float sca = (mode == 0) ? frcp(dnm[h]) * LOG2E : 1.0f;
#pragma unroll
          for (int r = 0; r < 4; r++) {
            int mrow = mbase + r;
            int b = mrow >> 10, s = mrow & 1023;
            float val = acc[mi][ni][r] + bn;
            float partner = __shfl_xor(val, 1);
            float ang = (float)(s >> 7) * freq;
            float sn = __sinf(ang), cs = __cosf(ang);
            float res = (n & 1) ? (partner * sn + val * cs) : (val * cs - partner * sn);
            res *= sca;
            size_t idx;
            if (mode == 0)
              idx = ((size_t)(b * NH + h) * NS + s) * NDH + d;
            else
              idx = ((size_t)((f * NB + b) * NH + h) * NS + s) * NDH + d;
            (mode == 0 ? qr : kr)[idx] = f2b(res);
          }
        } else {
          int vd = n - 512;
          int h = vd >> 6, d = vd & 63;
          int b = mbase >> 10, s0 = mbase & 1023;
          u16 pk[4];
#pragma unroll
          for (int r = 0; r < 4; r++) pk[r] = f2b(acc[mi][ni][r] + bn);
          u16* dst = vtr + ((size_t)((f * NB + b) * NH + h) * NDH + d) * NS + s0;
          *reinterpret_cast<ushort4*>(dst) = *reinterpret_cast<ushort4*>(pk);
        }
      }
  } else {  // ---------------- bias MLP path (f16 MFMA chain, log2e-folded) -------
    int id = (bid0 - 896) * 4 + wave;  // 8192 = b(4) x qt(64) x kt(32)
    int kt = id & 31, qt = (id >> 5) & 63, b = id >> 11;
    const float Y0 = 0.28209479177387814f;
    const float Y1 = 0.4886025119029199f;
    h16x4 A1 = {}, A2, A3;
#pragma unroll
    for (int r = 0; r < 4; r++) {
      A1[r] = (g == 0) ? (_Float16)W1[r * 16 + li] : (_Float16)0.0f;
      A2[r] = (_Float16)W2[(4 * g + r) * 16 + li];
      A3[r] = (li < 8) ? (_Float16)(W3[(4 * g + r) * 8 + li] * LOG2E) : (_Float16)0.0f;
    }
    f32x4 b1g = reinterpret_cast<const f32x4*>(b1)[g];
    f32x4 b2g = reinterpret_cast<const f32x4*>(b2)[g];
    f32x4 b3g = {0.f, 0.f, 0.f, 0.f};
    if (g < 2) b3g = reinterpret_cast<const f32x4*>(b3)[g] * LOG2E;
    const float4* crd4 = reinterpret_cast<const float4*>(coords);
    float4 cq = crd4[b * NS + qt * 16 + li];
    f32x4 zero = {0.f, 0.f, 0.f, 0.f};
    for (int gkc = 0; gkc < 4; gkc++) {
      unsigned int resw[4][4];
      float prev[4];
#pragma unroll
      for (int j = 0; j < 8; j++) {
        int k = kt * 32 + (j >> 2) * 16 + gkc * 4 + (j & 3);
        float4 ck = crd4[b * NS + k];
        float rx = cq.x - ck.x;
        float ry = cq.y - ck.y;
        float rz = cq.z - ck.z;
        float d2 = rx * rx + ry * ry + rz * rz;
        float inv = __builtin_amdgcn_rsqf(fmaxf(d2, 1e-20f));
        h16x4 B1 = {};
        if (g == 0) {
          B1[0] = (_Float16)Y0;
          B1[1] = (_Float16)(Y1 * ry * inv);
          B1[2] = (_Float16)(Y1 * rz * inv);
          B1[3] = (_Float16)(Y1 * rx * inv);
        }
        f32x4 c1 = mfma16(A1, B1, zero);
        h16x4 B2;
#pragma unroll
        for (int r = 0; r < 4; r++) {
          float a = c1[r] + b1g[r];
          B2[r] = (_Float16)(a * frcp(1.0f + __expf(-a)));
        }
        f32x4 c2 = mfma16(A2, B2, zero);
        h16x4 B3;
#pragma unroll
        for (int r = 0; r < 4; r++) {
          float a = c2[r] + b2g[r];
          B3[r] = (_Float16)(a * frcp(1.0f + __expf(-a)));
        }
        f32x4 c3 = mfma16(A3, B3, zero);
#pragma unroll
        for (int r = 0; r < 4; r++) {
          float val = c3[r] + b3g[r];
          if (j & 1)
            resw[r][j >> 1] = cvtpk(prev[r], val);
          else
            prev[r] = val;
        }
      }
      if (g < 2) {
        size_t coff = ((size_t)(qt * 32 + kt) * 64 + gkc * 16 + li) * 8;
#pragma unroll
        for (int r = 0; r < 4; r++) {
          u16* dst = biasF + (size_t)(b * NH + 4 * g + r) * 1048576 + coff;
          *reinterpret_cast<uint4*>(dst) = *reinterpret_cast<uint4*>(resw[r]);
        }
      }
    }
  }
}

// ---------------- out-projection GEMM (mode-2 only, m97 structure) ---------------
__global__ void __launch_bounds__(256) gemm_out_kernel(const u16* __restrict__ A,
                                                       const u16* __restrict__ Wt,
                                                       const float* __restrict__ bias,
                                                       float* __restrict__ outF) {
  __shared__ __align__(16) u16 sbuf[2 * 8192];
  const int N = 512, K = 512;
  int bid = blockIdx.x;
  int nt = N >> 7;
  int by = bid / nt, bx = bid % nt;
  int tid = threadIdx.x;
  int lane = tid & 63, wave = tid >> 6;
  int g = lane >> 4, li = lane & 15;
  int wr = (wave & 1) * 64, wc = (wave >> 1) * 64;
  f32x4 acc[4][4] = {};
  const u16* srcs[4];
  int dsts[4];
#pragma unroll
  for (int j = 0; j < 4; j++) {
    int c = wave * 4 + j;
    if (c < 8)
      srcs[j] = A + (size_t)(by * 128 + c * 16 + li) * K + g * 8;
    else
      srcs[j] = Wt + (size_t)(bx * 128 + (c - 8) * 16 + li) * K + g * 8;
    dsts[j] = c * 512 + lane * 8;
  }
#pragma unroll
  for (int j = 0; j < 4; j++) gl16(srcs[j], sbuf + dsts[j]);
  for (int t = 0; t < 16; t++) {
    int p = t & 1;
    if (t < 15) {
#pragma unroll
      for (int j = 0; j < 4; j++)
        gl16(srcs[j] + (t + 1) * 32, sbuf + (p ^ 1) * 8192 + dsts[j]);
      asm volatile("s_waitcnt vmcnt(4)" ::: "memory");
    } else {
      asm volatile("s_waitcnt vmcnt(0)" ::: "memory");
    }
    __builtin_amdgcn_s_barrier();
    __builtin_amdgcn_sched_barrier(0);
    const u16* bufb = sbuf + p * 8192;
    v8s a[4], b[4];
#pragma unroll
    for (int mi = 0; mi < 4; mi++)
      a[mi] = *reinterpret_cast<const v8s*>(bufb + ((wr >> 4) + mi) * 512 + lane * 8);
#pragma unroll
    for (int ni = 0; ni < 4; ni++)
      b[ni] = *reinterpret_cast<const v8s*>(bufb + 4096 + ((wc >> 4) + ni) * 512 + lane * 8);
    __builtin_amdgcn_s_setprio(1);
#pragma unroll
    for (int mi = 0; mi < 4; mi++)
#pragma unroll
      for (int ni = 0; ni < 4; ni++)
        acc[mi][ni] = __builtin_amdgcn_mfma_f32_16x16x32_bf16(a[mi], b[ni], acc[mi][ni], 0, 0, 0);
    __builtin_amdgcn_s_setprio(0);
    __builtin_amdgcn_s_barrier();
  }
#pragma unroll
  for (int mi = 0; mi < 4; mi++)
#pragma unroll
    for (int ni = 0; ni < 4; ni++) {
      int n = bx * 128 + wc + ni * 16 + li;
      float bn = bias[n];
      int mbase = by * 128 + wr + mi * 16 + 4 * g;
#pragma unroll
      for (int r = 0; r < 4; r++)
        outF[(size_t)(mbase + r) * N + n] = acc[mi][ni][r] + bn;
    }
}

// ---------------- fused flash attention (R15-proven: double-buffer, fexp2) -------
#define ATTN_LDSB 12288  // u16 per buffer (24KB)
__global__ void __launch_bounds__(768, 6) attn_kernel(const u16* __restrict__ q,
                                                      const u16* __restrict__ kmat,
                                                      const u16* __restrict__ vt,
                                                      const u16* __restrict__ biasF,
                                                      const float* __restrict__ fw,
                                                      u16* __restrict__ attno) {
  __shared__ __align__(16) u16 sbuf[2 * ATTN_LDSB];
  int d = blockIdx.x;
  int x = d & 7, u = d >> 3;
  int bh = x * 4 + (u & 3);  // 16 blocks per bh share one XCD
  int qb = u >> 2;
  int h = bh & 7, b = bh >> 3;
  int wave = threadIdx.x >> 6, lane = threadIdx.x & 63;
  int g = lane >> 4, li = lane & 15;
  int ff = wave >> 2, qtl = wave & 3;
  int qt = qb * 4 + qtl;

  float f0 = fw[0], f1 = fw[1], f2v = fw[2];
  float mxg = fmaxf(fmaxf(f0, f1), f2v);
  float e0 = __expf(f0 - mxg), e1 = __expf(f1 - mxg), e2 = __expf(f2v - mxg);
  float es = e0 + e1 + e2;
  float gate = (ff == 0 ? e0 : (ff == 1 ? e1 : e2)) / es;

  const u16* qbase = q + ((size_t)bh * NS + qt * 16 + li) * NDH + g * 8;
  v8s qa0 = *reinterpret_cast<const v8s*>(qbase);
  v8s qa1 = *reinterpret_cast<const v8s*>(qbase + 32);
  const u16* bfrag = biasF + (size_t)bh * 1048576 + (size_t)qt * 16384;

  auto stage = [&](int kt, int p) {
    int k0 = kt * 32;
    u16* bufb = sbuf + p * ATTN_LDSB;
#pragma unroll
    for (int j = 0; j < 2; j++) {
      int c = wave * 2 + j;
      if (c < 12) {
        int cf = c >> 2, kks = (c >> 1) & 1, hf = c & 1;
        const u16* src = kmat + ((size_t)(cf * 32 + bh) * NS + k0 + kks * 16 + li) * NDH +
                         hf * 32 + g * 8;
        gl16(src, bufb + cf * 2048 + (c & 3) * 512 + lane * 8);
      } else {
        int cc = c - 12, cf = cc >> 2, ni = cc & 3;
        const u16* src = vt + ((size_t)(cf * 32 + bh) * NDH + ni * 16 + li) * NS + k0 + g * 8;
        gl16(src, bufb + 6144 + cf * 2048 + ni * 512 + lane * 8);
      }
    }
  };

  float m = 0.f;   // wave-uniform deferred max (log2 units)
  float lr = 0.f;
  f32x4 o[4] = {};
  f32x4 zero = {0.f, 0.f, 0.f, 0.f};
  int s0lane = ((g & 1) << 5) + li;  // fallback path only
  int kksT = g >> 1;

  stage(0, 0);

  for (int t = 0; t < 32; t++) {
    int p = t & 1;
    v8s bb = *reinterpret_cast<const v8s*>(bfrag + ((size_t)t * 64 + lane) * 8);
    if (t < 31) {
      stage(t + 1, p ^ 1);
      asm volatile("s_waitcnt vmcnt(2)" ::: "memory");
    } else {
      asm volatile("s_waitcnt vmcnt(0)" ::: "memory");
    }
    __builtin_amdgcn_s_barrier();
    __builtin_amdgcn_sched_barrier(0);
    const u16* bufb = sbuf + p * ATTN_LDSB;
    v8s kf[2][2];
#pragma unroll
    for (int kks = 0; kks < 2; kks++)
#pragma unroll
      for (int hf = 0; hf < 2; hf++)
        kf[kks][hf] = *reinterpret_cast<const v8s*>(
            bufb + ff * 2048 + (kks * 2 + hf) * 512 + lane * 8);
    float pv[2][4];
    __builtin_amdgcn_s_setprio(1);
#pragma unroll
    for (int kks = 0; kks < 2; kks++) {
      f32x4 sc = __builtin_amdgcn_mfma_f32_16x16x32_bf16(kf[kks][0], qa0, zero, 0, 0, 0);
      sc = __builtin_amdgcn_mfma_f32_16x16x32_bf16(kf[kks][1], qa1, sc, 0, 0, 0);
#pragma unroll
      for (int r = 0; r < 4; r++)
        pv[kks][r] = sc[r] + b2f((u16)bb[kks * 4 + r]);  // q,bias pre-scaled by log2e
    }
    __builtin_amdgcn_s_setprio(0);
    float pmax = fmaxf(fmaxf(fmaxf(pv[0][0], pv[0][1]), pv[0][2]),
                       fmaxf(fmaxf(pv[0][3], pv[1][0]), pv[1][1]));
    pmax = fmaxf(fmaxf(pmax, pv[1][2]), pv[1][3]);
    if (!__all(pmax - m <= 11.0f)) {  // rare: raise wave-uniform max (2^11 headroom)
      float rm = pmax;
      rm = fmaxf(rm, __shfl_xor(rm, 1));
      rm = fmaxf(rm, __shfl_xor(rm, 2));
      rm = fmaxf(rm, __shfl_xor(rm, 4));
      rm = fmaxf(rm, __shfl_xor(rm, 8));
      rm = fmaxf(rm, __shfl_xor(rm, 16));
      rm = fmaxf(rm, __shfl_xor(rm, 32));
      float sc2 = fexp2(m - rm);
      lr *= sc2;
#pragma unroll
      for (int ni = 0; ni < 4; ni++)
#pragma unroll
        for (int r = 0; r < 4; r++) o[ni][r] *= sc2;
      m = rm;
    }
    float p2[2][4];
#pragma unroll
    for (int kks = 0; kks < 2; kks++)
#pragma unroll
      for (int r = 0; r < 4; r++) {
        p2[kks][r] = fexp2(pv[kks][r] - m);  // single v_exp_f32
        lr += p2[kks][r];
      }
    unsigned int pA0 = cvtpk(p2[0][0], p2[0][1]);
    unsigned int pA1 = cvtpk(p2[0][2], p2[0][3]);
    unsigned int pB0 = cvtpk(p2[1][0], p2[1][1]);
    unsigned int pB1 = cvtpk(p2[1][2], p2[1][3]);
    int warr[4];
#if __has_builtin(__builtin_amdgcn_permlane32_swap) && \
    __has_builtin(__builtin_amdgcn_permlane16_swap)
    {
      u32x2 r0 = __builtin_amdgcn_permlane32_swap(pA0, pB0, false, false);
      u32x2 r1 = __builtin_amdgcn_permlane32_swap(pA1, pB1, false, false);
      u32x2 s0 = __builtin_amdgcn_permlane16_swap(r0[0], r0[1], false, false);
      u32x2 s1 = __builtin_amdgcn_permlane16_swap(r1[0], r1[1], false, false);
      warr[0] = s0[0];
      warr[1] = s1[0];
      warr[2] = s0[1];
      warr[3] = s1[1];
    }
#else
    {
      int a00 = __shfl((int)pA0, s0lane), a01 = __shfl((int)pA1, s0lane);
      int a10 = __shfl((int)pB0, s0lane), a11 = __shfl((int)pB1, s0lane);
      int c00 = __shfl((int)pA0, s0lane + 16), c01 = __shfl((int)pA1, s0lane + 16);
      int c10 = __shfl((int)pB0, s0lane + 16), c11 = __shfl((int)pB1, s0lane + 16);
      warr[0] = kksT ? a10 : a00;
      warr[1] = kksT ? a11 : a01;
      warr[2] = kksT ? c10 : c00;
      warr[3] = kksT ? c11 : c01;
    }
#endif
    v8s pa = *reinterpret_cast<v8s*>(warr);
    __builtin_amdgcn_s_setprio(1);
#pragma unroll
    for (int ni = 0; ni < 4; ni++) {
      v8s vb = *reinterpret_cast<const v8s*>(bufb + 6144 + ff * 2048 + ni * 512 + lane * 8);
      o[ni] = __builtin_amdgcn_mfma_f32_16x16x32_bf16(pa, vb, o[ni], 0, 0, 0);
    }
    __builtin_amdgcn_s_setprio(0);
    __builtin_amdgcn_s_barrier();
  }
  float l = lr;
  l += __shfl_xor(l, 16);
  l += __shfl_xor(l, 32);
  float scl = gate / l;
  float srow[4];
#pragma unroll
  for (int r = 0; r < 4; r++)
    srow[r] = __shfl(scl, (lane & 48) | (((lane >> 2) & 12) + r));
  float out[4][4];
#pragma unroll
  for (int ni = 0; ni < 4; ni++)
#pragma unroll
    for (int r = 0; r < 4; r++) out[ni][r] = o[ni][r] * srow[r];

  float* part = reinterpret_cast<float*>(sbuf);  // [8][16][68] padded
  if (ff > 0) {
    int fq = (ff - 1) * 4 + qtl;
#pragma unroll
    for (int ni = 0; ni < 4; ni++)
#pragma unroll
      for (int r = 0; r < 4; r++)
        part[fq * 1088 + (4 * g + r) * 68 + ni * 16 + li] = out[ni][r];
  }
  __syncthreads();
  if (ff == 0) {
#pragma unroll
    for (int ni = 0; ni < 4; ni++)
#pragma unroll
      for (int r = 0; r < 4; r++) {
        float v = out[ni][r] + part[qtl * 1088 + (4 * g + r) * 68 + ni * 16 + li] +
                  part[(4 + qtl) * 1088 + (4 * g + r) * 68 + ni * 16 + li];
        attno[((size_t)(b * NS + qt * 16 + 4 * g + r)) * ND + h * NDH + ni * 16 + li] =
            f2b(v);
      }
  }
}

extern "C" void kernel_launch(void* const* d_in, const int* in_sizes, int n_in,
                              void* d_out, int out_size, void* d_ws, size_t ws_size,
                              hipStream_t stream) {
  const float* x0 = (const float*)d_in[0];
  const float* v0 = (const float*)d_in[1];
  const float* cf = (const float*)d_in[2];
  const float* qd = (const float*)d_in[3];
  const float* Wq = (const float*)d_in[4];
  const float* bq = (const float*)d_in[5];
  const float* Wkv = (const float*)d_in[6];
  const float* bkv = (const float*)d_in[7];
  const float* Wo = (const float*)d_in[8];
  const float* bo = (const float*)d_in[9];
  const float* fw = (const float*)d_in[10];
  const float* dnm = (const float*)d_in[11];
  const float* W1 = (const float*)d_in[12];
  const float* b1 = (const float*)d_in[13];
  const float* W2 = (const float*)d_in[14];
  const float* b2 = (const float*)d_in[15];
  const float* W3 = (const float*)d_in[16];
  const float* b3 = (const float*)d_in[17];

  char* ws = (char*)d_ws;
  size_t off = 0;
  auto alloc = [&](size_t bytes) -> void* {
    void* p = ws + off;
    off = (off + bytes + 255) & ~(size_t)255;
    return p;
  };
  const size_t E = 4096ull * 512;
  u16* Aq = (u16*)alloc(E * 2);
  u16* Af = (u16*)alloc(3 * E * 2);  // contiguous after Aq (pre_kernel relies on this)
  u16* Wqt = (u16*)alloc(262144ull * 2);
  u16* Wkvt = (u16*)alloc(3ull * 524288 * 2);
  u16* Wot = (u16*)alloc(262144ull * 2);
  float* crd = (float*)alloc(4096ull * 4 * 4);
  u16* qr = (u16*)alloc(E * 2);
  u16* kr = (u16*)alloc(3 * E * 2);
  u16* vtr = (u16*)alloc(3 * E * 2);
  u16* biasF = (u16*)alloc(33554432ull * 2);
  u16* attno = (u16*)alloc(E * 2);
  (void)ws_size; (void)in_sizes; (void)n_in; (void)out_size; (void)Af;

  pre_kernel<<<6145, 256, 0, stream>>>(qd, x0, v0, cf, Aq, crd, Wq, Wkv, Wo,
                                       Wqt, Wkvt, Wot);
  mid_kernel<<<2944, 256, 0, stream>>>(Aq, Wqt, bq, dnm, qr, Af, Wkvt, bkv, kr, vtr,
                                       crd, W1, b1, W2, b2, W3, b3, biasF);
  attn_kernel<<<512, 768, 0, stream>>>(qr, kr, vtr, biasF, fw, attno);
  gemm_out_kernel<<<128, 256, 0, stream>>>(attno, Wot, bo, (float*)d_out);
}